// Round 6
// baseline (2686.034 us; speedup 1.0000x reference)
//
#include <hip/hip_runtime.h>
#include <hip/hip_bf16.h>
#include <math.h>

#define BB 256
#define TT 64
#define UU 512
#define XWD 33554432   // per-dir xw elements (64*256*2048)
#define WSTR 520       // LDS weight row stride (512 + 8 pad)

typedef __hip_bfloat16 bf16;
typedef __attribute__((ext_vector_type(8))) short sh8;     // 8 x bf16
typedef __attribute__((ext_vector_type(4))) short sh4;     // 4 x bf16
typedef __attribute__((ext_vector_type(4))) float floatx4; // MFMA acc

__device__ __forceinline__ float bf2f(short s) {
    union { unsigned int u; float f; } v;
    v.u = ((unsigned int)(unsigned short)s) << 16;
    return v.f;
}
__device__ __forceinline__ short f2bf_bits(float f) {
    union { float f; unsigned u; } v; v.f = f;
    unsigned rr = v.u + 0x7fff + ((v.u >> 16) & 1);   // RNE, matches __float2bfloat16
    return (short)(rr >> 16);
}
__device__ __forceinline__ float fsig(float x)  { return 1.0f / (1.0f + __expf(-x)); }
__device__ __forceinline__ float ftanh(float x) { return 2.0f / (1.0f + __expf(-2.0f * x)) - 1.0f; }

// async global->LDS, 16B per lane. LDS dest must be wave-uniform base + lane*16.
#define GLDS(gp, lp) __builtin_amdgcn_global_load_lds( \
    (const __attribute__((address_space(1))) unsigned int*)(const void*)(gp), \
    (__attribute__((address_space(3))) unsigned int*)(void*)(lp), 16, 0, 0)

// ---------------- transpose + fp32->bf16 convert ----------------
__global__ void transpose_conv_kernel(const float* __restrict__ in, bf16* __restrict__ out,
                                      int K, int N, int out_stride) {
    __shared__ float tile[32][33];
    int k0 = blockIdx.y * 32;
    int n0 = blockIdx.x * 32;
    int tid = threadIdx.x;
    int nn = tid & 31, kk = tid >> 5;
    #pragma unroll
    for (int j = 0; j < 4; ++j)
        tile[kk + j * 8][nn] = in[(size_t)(k0 + kk + j * 8) * N + n0 + nn];
    __syncthreads();
    int kk2 = tid & 31, nn2 = tid >> 5;
    #pragma unroll
    for (int j = 0; j < 4; ++j)
        out[(size_t)(n0 + nn2 + j * 8) * out_stride + k0 + kk2] =
            __float2bfloat16(tile[kk2][nn2 + j * 8]);
}

// ---------------- mean-pool over 10x10 spatial ----------------
__global__ void pool_kernel(const float* __restrict__ enc, float* __restrict__ pooled) {
    int b = blockIdx.y;
    int e = blockIdx.x * 256 + threadIdx.x;
    const float* p = enc + (size_t)b * 100 * 2048 + e;
    float s = 0.f;
    #pragma unroll 4
    for (int i = 0; i < 100; ++i) s += p[(size_t)i * 2048];
    pooled[(size_t)b * 2048 + e] = s * 0.01f;
}

// ---------------- embedding gather -> bf16, [t][b][256] layout ----------------
__global__ void embed_kernel(const int* __restrict__ seq, const float* __restrict__ emb,
                             bf16* __restrict__ tok) {
    int i = blockIdx.x;            // b*T + t
    int e = threadIdx.x;
    int b = i >> 6, t = i & 63;
    tok[((size_t)t * BB + b) * 256 + e] = __float2bfloat16(emb[(size_t)seq[i] * 256 + e]);
}

// ---------------- LDS-staged GEMM: out = act(A @ Wt^T + b) ----------------
__global__ __launch_bounds__(256)
void gemm_tile(const bf16* __restrict__ A, const bf16* __restrict__ Wt,
               const float* __restrict__ bias, bf16* __restrict__ out,
               int M, int N, int K, int relu, int mode) {
    __shared__ __align__(16) bf16 As[128 * 32];
    __shared__ __align__(16) bf16 Bs[128 * 32];
    const int tid = threadIdx.x;
    const int w = tid >> 6, lane = tid & 63;
    const int lm = lane & 15, q = lane >> 4;
    const int m0 = blockIdx.y * 128;
    const int n0 = blockIdx.x * 128;
    const int wm = (w & 1) * 64, wn = (w >> 1) * 64;

    const int srow = tid >> 2;
    const int sk8  = (tid & 3) * 8;
    const bf16* ga0 = A  + (size_t)(m0 + srow) * K + sk8;
    const bf16* ga1 = A  + (size_t)(m0 + 64 + srow) * K + sk8;
    const bf16* gb0 = Wt + (size_t)(n0 + srow) * K + sk8;
    const bf16* gb1 = Wt + (size_t)(n0 + 64 + srow) * K + sk8;
    bf16* la0 = As + tid * 8;
    bf16* la1 = As + 2048 + tid * 8;
    bf16* lb0 = Bs + tid * 8;
    bf16* lb1 = Bs + 2048 + tid * 8;

    floatx4 acc[4][4];
    #pragma unroll
    for (int i = 0; i < 4; ++i)
        #pragma unroll
        for (int j = 0; j < 4; ++j) acc[i][j] = (floatx4){0.f, 0.f, 0.f, 0.f};

    const bf16* ra[4];
    const bf16* rb[4];
    #pragma unroll
    for (int i = 0; i < 4; ++i) ra[i] = As + (wm + i * 16 + lm) * 32 + q * 8;
    #pragma unroll
    for (int j = 0; j < 4; ++j) rb[j] = Bs + (wn + j * 16 + lm) * 32 + q * 8;

    for (int k0 = 0; k0 < K; k0 += 32) {
        GLDS(ga0 + k0, la0);
        GLDS(ga1 + k0, la1);
        GLDS(gb0 + k0, lb0);
        GLDS(gb1 + k0, lb1);
        __syncthreads();
        sh8 af[4], bfr[4];
        #pragma unroll
        for (int i = 0; i < 4; ++i) af[i] = *(const sh8*)ra[i];
        #pragma unroll
        for (int j = 0; j < 4; ++j) bfr[j] = *(const sh8*)rb[j];
        #pragma unroll
        for (int i = 0; i < 4; ++i)
            #pragma unroll
            for (int j = 0; j < 4; ++j)
                acc[i][j] = __builtin_amdgcn_mfma_f32_16x16x32_bf16(af[i], bfr[j], acc[i][j], 0, 0, 0);
        __syncthreads();
    }

    if (mode == 0) {
        #pragma unroll
        for (int i = 0; i < 4; ++i)
            #pragma unroll
            for (int j = 0; j < 4; ++j) {
                int n = n0 + wn + j * 16 + lm;
                float bv = bias[n];
                #pragma unroll
                for (int r = 0; r < 4; ++r) {
                    int m = m0 + wm + i * 16 + q * 4 + r;
                    float v = acc[i][j][r] + bv;
                    if (relu) v = fmaxf(v, 0.f);
                    out[(size_t)m * N + n] = __float2bfloat16(v);
                }
            }
    } else {
        #pragma unroll
        for (int i = 0; i < 4; ++i) {
            int mb = m0 + wm + i * 16 + q * 4;
            int t = mb >> 8;
            int bq = (mb >> 2) & 63;
            #pragma unroll
            for (int j = 0; j < 4; ++j) {
                int n = n0 + wn + j * 16 + lm;
                float bv = bias[n];
                size_t base = ((((size_t)(t * 64 + bq) * 32 + ((n >> 4) & 31)) * 16
                               + (n & 15)) * 16) + (n >> 9) * 4;
                sh4 sv;
                #pragma unroll
                for (int r = 0; r < 4; ++r)
                    sv[r] = f2bf_bits(acc[i][j][r] + bv);
                *(sh4*)(out + base) = sv;
            }
        }
    }
}

// ---------------- flag barrier: 32 x 4B flags packed in ONE 128B line per group ------
// arrive: one release STORE to own word (distinct words, no RMW serialization).
// wait: wave 0's lanes 0..31 poll the single line in parallel; one load-round/iter.
// Values are monotonic step counts; layer 2 continues at TT, so no resets needed.
__device__ __forceinline__ void bar_arrive(unsigned* myflag, unsigned val) {
    __syncthreads();   // all waves' h stores issued before signal; release orders them
    if (threadIdx.x == 0)
        __hip_atomic_store(myflag, val, __ATOMIC_RELEASE, __HIP_MEMORY_SCOPE_AGENT);
}
__device__ __forceinline__ void bar_wait(unsigned* flagbase, unsigned target) {
    if (threadIdx.x < 64) {
        unsigned* my = flagbase + (threadIdx.x & 31);
        for (;;) {
            unsigned v = __hip_atomic_load(my, __ATOMIC_RELAXED, __HIP_MEMORY_SCOPE_AGENT);
            if (__all(v >= target)) break;
            __builtin_amdgcn_s_sleep(1);
        }
        if (threadIdx.x == 0)
            __builtin_amdgcn_fence(__ATOMIC_ACQUIRE, "agent");
    }
    __syncthreads();
}

// ---------------- persistent LSTM: whole 64-step sequence in one launch ----------------
// grid (32 u-tiles, 4 b-groups, 2 dirs) = 256 blocks, 512 thr, ~100KB LDS -> 1 blk/CU.
// Per block: Wh tile in LDS, seq tile in LDS, c/h-carry in regs. Per step: wait ->
// hoisted h loads -> MFMA -> part-exchange -> epilogue (NT stores) -> arrive (flag
// store) -> xw prefetch for next step (hidden under barrier skew).
__global__ __launch_bounds__(512, 2)
void lstm_seq(const bf16* __restrict__ xw, const bf16* __restrict__ Wht,
              const int* __restrict__ seq, bf16* __restrict__ h0b,
              bf16* __restrict__ h1b, bf16* __restrict__ seqout,
              unsigned* __restrict__ gflags, int tbase) {
    const int dir = blockIdx.z;
    const int u0 = blockIdx.x * 16;
    const int tid = threadIdx.x;
    const int w = tid >> 6, lane = tid & 63;
    const int lm = lane & 15, q = lane >> 4;
    const int kh = w >> 2;           // k-half
    const int wb = w & 3;            // b-group wave
    const int b0blk = blockIdx.y * 64;
    const int b0w = b0blk + wb * 16;
    unsigned* flagbase = gflags + (blockIdx.z * 4 + blockIdx.y) * 32;  // one 128B line
    unsigned* myflag   = flagbase + blockIdx.x;

    __shared__ float part[4 * 64 * 17];          // 17408 B
    __shared__ __align__(16) bf16 lW[64 * WSTR]; // 66560 B
    __shared__ int sq[TT * 64];                  // 16384 B  (~100KB total -> 1 blk/CU)

    const size_t hdb = (size_t)dir * BB * UU;
    const int koff = kh * 256;                   // 8 kc * 32
    const bf16* Wd = Wht + (size_t)dir * 2048 * UU;

    // one-time seq preload: sq[t*64 + bb] = seq[(b0blk+bb)*TT + t]
    for (int i = tid; i < TT * 64; i += 512) {
        int tt = i >> 6, bb = i & 63;
        sq[i] = seq[(b0blk + bb) * TT + tt];
    }
    // one-time weight preload: LDS[g*16+lmr][k] = Wd[(g*512 + u0 + lmr)*512 + k]
    {
        int row = tid >> 3;                  // 0..63
        int ck  = (tid & 7) * 64;
        int g = row >> 4, lmr = row & 15;
        const bf16* gsrc = Wd + (size_t)(g * UU + u0 + lmr) * UU + ck;
        bf16* ldst = lW + row * WSTR + ck;
        #pragma unroll
        for (int j = 0; j < 8; ++j)
            *(sh8*)(ldst + j * 8) = *(const sh8*)(gsrc + j * 8);
    }
    __syncthreads();

    const bf16* lwp0 = lW + (0 * 16 + lm) * WSTR + q * 8 + koff;
    const bf16* lwp1 = lW + (1 * 16 + lm) * WSTR + q * 8 + koff;
    const bf16* lwp2 = lW + (2 * 16 + lm) * WSTR + q * 8 + koff;
    const bf16* lwp3 = lW + (3 * 16 + lm) * WSTR + q * 8 + koff;

    // register state for this lane's (b = b0w + q*4 + r, u = u0 + lm) tile (kh=0 waves)
    float creg[4] = {0.f, 0.f, 0.f, 0.f};
    float hreg[4] = {0.f, 0.f, 0.f, 0.f};

    // xw prefetch for step 0 (kh=0 waves only)
    sh8 x0p = (sh8)0, x1p = (sh8)0;
    if (kh == 0) {
        const int t0s = dir ? (TT - 1) : 0;
        const bf16* xwp = xw + (size_t)dir * XWD
            + (((size_t)(t0s * 64 + (b0w >> 2) + q) * 32 + (u0 >> 4)) * 16 + lm) * 16;
        x0p = *(const sh8*)xwp;
        x1p = *(const sh8*)(xwp + 8);
    }

    for (int s = 0; s < TT; ++s) {
        const int t = dir ? (TT - 1 - s) : s;
        const bf16* hin = (s & 1) ? h1b : h0b;
        bf16*      hout = (s & 1) ? h0b : h1b;

        if (s) bar_wait(flagbase, (unsigned)(tbase + s));

        // hoisted h loads: all 8 issued back-to-back (one latency round)
        const bf16* hA = hin + hdb + (size_t)(b0w + lm) * UU + q * 8 + koff;
        sh8 hv[8];
        #pragma unroll
        for (int kc = 0; kc < 8; ++kc) hv[kc] = *(const sh8*)(hA + kc * 32);

        floatx4 acc0, acc1, acc2, acc3;
        if (kh == 0) {
            acc0 = (floatx4){bf2f(x0p[0]), bf2f(x0p[1]), bf2f(x0p[2]), bf2f(x0p[3])};
            acc1 = (floatx4){bf2f(x0p[4]), bf2f(x0p[5]), bf2f(x0p[6]), bf2f(x0p[7])};
            acc2 = (floatx4){bf2f(x1p[0]), bf2f(x1p[1]), bf2f(x1p[2]), bf2f(x1p[3])};
            acc3 = (floatx4){bf2f(x1p[4]), bf2f(x1p[5]), bf2f(x1p[6]), bf2f(x1p[7])};
        } else {
            acc0 = acc1 = acc2 = acc3 = (floatx4){0.f, 0.f, 0.f, 0.f};
        }

        #pragma unroll
        for (int kc = 0; kc < 8; ++kc) {
            sh8 a0 = *(const sh8*)(lwp0 + kc * 32);
            sh8 a1 = *(const sh8*)(lwp1 + kc * 32);
            sh8 a2 = *(const sh8*)(lwp2 + kc * 32);
            sh8 a3 = *(const sh8*)(lwp3 + kc * 32);
            acc0 = __builtin_amdgcn_mfma_f32_16x16x32_bf16(hv[kc], a0, acc0, 0, 0, 0);
            acc1 = __builtin_amdgcn_mfma_f32_16x16x32_bf16(hv[kc], a1, acc1, 0, 0, 0);
            acc2 = __builtin_amdgcn_mfma_f32_16x16x32_bf16(hv[kc], a2, acc2, 0, 0, 0);
            acc3 = __builtin_amdgcn_mfma_f32_16x16x32_bf16(hv[kc], a3, acc3, 0, 0, 0);
        }

        if (kh == 1) {
            float* pp = part + (wb * 64 + lane) * 17;
            #pragma unroll
            for (int r = 0; r < 4; ++r) {
                pp[r] = acc0[r]; pp[4 + r] = acc1[r];
                pp[8 + r] = acc2[r]; pp[12 + r] = acc3[r];
            }
        }
        __syncthreads();
        if (kh == 0) {
            const float* pp = part + (wb * 64 + lane) * 17;
            #pragma unroll
            for (int r = 0; r < 4; ++r) {
                acc0[r] += pp[r]; acc1[r] += pp[4 + r];
                acc2[r] += pp[8 + r]; acc3[r] += pp[12 + r];
            }
            const int uu = u0 + lm;
            #pragma unroll
            for (int r = 0; r < 4; ++r) {
                int b = b0w + q * 4 + r;
                bool m = (sq[t * 64 + wb * 16 + q * 4 + r] != 0);
                float cp = creg[r];
                float cn = fsig(acc1[r]) * cp + fsig(acc0[r]) * ftanh(acc2[r]);
                float hn = fsig(acc3[r]) * ftanh(cn);
                float hv2 = m ? hn : hreg[r];
                creg[r] = m ? cn : cp;
                hreg[r] = hv2;
                size_t off = hdb + (size_t)b * UU + uu;
                short hb = f2bf_bits(hv2);
                __builtin_nontemporal_store(hb, (short*)&hout[off]);
                if (seqout)
                    __builtin_nontemporal_store(hb,
                        (short*)&seqout[((size_t)t * BB + b) * 1024 + dir * UU + uu]);
            }
        }
        bar_arrive(myflag, (unsigned)(tbase + s + 1));

        // prefetch next step's xw (h-independent; hides under barrier skew)
        if (kh == 0 && s + 1 < TT) {
            const int tn = dir ? (TT - 2 - s) : (s + 1);
            const bf16* xwp = xw + (size_t)dir * XWD
                + (((size_t)(tn * 64 + (b0w >> 2) + q) * 32 + (u0 >> 4)) * 16 + lm) * 16;
            x0p = *(const sh8*)xwp;
            x1p = *(const sh8*)(xwp + 8);
        }
    }
}

// ---------------- feats = [pooled | h2f | h2b] (bf16) ----------------
__global__ void concat_kernel(const float* __restrict__ pooled, const bf16* __restrict__ h2,
                              bf16* __restrict__ feats) {
    int b = blockIdx.x;
    for (int j = threadIdx.x; j < 3072; j += 256) {
        bf16 v;
        if (j < 2048) v = __float2bfloat16(pooled[(size_t)b * 2048 + j]);
        else {
            int u = j - 2048;
            int dir = u >> 9;
            int uu = u & 511;
            v = h2[((size_t)dir * BB + b) * UU + uu];
        }
        feats[(size_t)b * 3072 + j] = v;
    }
}

// ---------------- out = sigmoid(x2 @ W3 + b3), K=512 ----------------
__global__ void final_kernel(const bf16* __restrict__ x2, const float* __restrict__ W3,
                             const float* __restrict__ b3, float* __restrict__ out) {
    int b = blockIdx.x;
    int tid = threadIdx.x;
    float v = __bfloat162float(x2[(size_t)b * 512 + tid]) * W3[tid]
            + __bfloat162float(x2[(size_t)b * 512 + 256 + tid]) * W3[256 + tid];
    for (int off = 32; off > 0; off >>= 1) v += __shfl_down(v, off, 64);
    __shared__ float wsum[4];
    if ((tid & 63) == 0) wsum[tid >> 6] = v;
    __syncthreads();
    if (tid == 0) {
        float sum = wsum[0] + wsum[1] + wsum[2] + wsum[3] + b3[0];
        out[b] = 1.0f / (1.0f + expf(-sum));
    }
}

extern "C" void kernel_launch(void* const* d_in, const int* in_sizes, int n_in,
                              void* d_out, int out_size, void* d_ws, size_t ws_size,
                              hipStream_t stream) {
    const float* enc    = (const float*)d_in[0];
    const int*   seq    = (const int*)  d_in[1];
    const float* emb    = (const float*)d_in[2];
    const float* l1f_Wi = (const float*)d_in[3];
    const float* l1f_Wh = (const float*)d_in[4];
    const float* l1f_b  = (const float*)d_in[5];
    const float* l1b_Wi = (const float*)d_in[6];
    const float* l1b_Wh = (const float*)d_in[7];
    const float* l1b_b  = (const float*)d_in[8];
    const float* l2f_Wi = (const float*)d_in[9];
    const float* l2f_Wh = (const float*)d_in[10];
    const float* l2f_b  = (const float*)d_in[11];
    const float* l2b_Wi = (const float*)d_in[12];
    const float* l2b_Wh = (const float*)d_in[13];
    const float* l2b_b  = (const float*)d_in[14];
    const float* W1     = (const float*)d_in[15];
    const float* b1     = (const float*)d_in[16];
    const float* W2     = (const float*)d_in[17];
    const float* b2     = (const float*)d_in[18];
    const float* W3     = (const float*)d_in[19];
    const float* b3     = (const float*)d_in[20];

    // ---- workspace layout ----
    char* p = (char*)d_ws;
    bf16* tok      = (bf16*)p;  p += (size_t)TT * BB * 256 * 2;        // [t][b][256]
    bf16* lstm1out = (bf16*)p;  p += (size_t)TT * BB * 1024 * 2;       // [t][b][1024]
    bf16* xw       = (bf16*)p;  p += (size_t)2 * XWD * 2;              // mode-2 perm
    bf16* Wh1t     = (bf16*)p;  p += (size_t)2 * 2048 * 512 * 2;
    bf16* Wh2t     = (bf16*)p;  p += (size_t)2 * 2048 * 512 * 2;
    bf16* Wi1t     = (bf16*)p;  p += (size_t)2 * 2048 * 256 * 2;
    bf16* Wi2t     = (bf16*)p;  p += (size_t)2 * 2048 * 1024 * 2;
    bf16* W1t      = (bf16*)p;  p += (size_t)1024 * 3072 * 2;
    bf16* W2t      = (bf16*)p;  p += (size_t)512 * 1024 * 2;
    float* pooled  = (float*)p; p += (size_t)BB * 2048 * 4;
    bf16* feats    = (bf16*)p;  p += (size_t)BB * 3072 * 2;
    bf16* x1       = (bf16*)p;  p += (size_t)BB * 1024 * 2;
    bf16* x2       = (bf16*)p;  p += (size_t)BB * 512 * 2;
    bf16* hb0      = (bf16*)p;  p += (size_t)2 * BB * UU * 2;
    bf16* hb1      = (bf16*)p;  p += (size_t)2 * BB * UU * 2;
    unsigned* gflags = (unsigned*)p; p += 8 * 128;                     // 8 grp x 1 line

    // ---- one-time setup ----
    hipMemsetAsync(gflags, 0, 8 * 128, stream);

    transpose_conv_kernel<<<dim3(64, 16), 256, 0, stream>>>(l1f_Wh, Wh1t,                    512, 2048, 512);
    transpose_conv_kernel<<<dim3(64, 16), 256, 0, stream>>>(l1b_Wh, Wh1t + (size_t)2048*512, 512, 2048, 512);
    transpose_conv_kernel<<<dim3(64, 16), 256, 0, stream>>>(l2f_Wh, Wh2t,                    512, 2048, 512);
    transpose_conv_kernel<<<dim3(64, 16), 256, 0, stream>>>(l2b_Wh, Wh2t + (size_t)2048*512, 512, 2048, 512);
    transpose_conv_kernel<<<dim3(64, 8),  256, 0, stream>>>(l1f_Wi, Wi1t,                    256, 2048, 256);
    transpose_conv_kernel<<<dim3(64, 8),  256, 0, stream>>>(l1b_Wi, Wi1t + (size_t)2048*256, 256, 2048, 256);
    transpose_conv_kernel<<<dim3(64, 32), 256, 0, stream>>>(l2f_Wi, Wi2t,                     1024, 2048, 1024);
    transpose_conv_kernel<<<dim3(64, 32), 256, 0, stream>>>(l2b_Wi, Wi2t + (size_t)2048*1024, 1024, 2048, 1024);
    transpose_conv_kernel<<<dim3(32, 96), 256, 0, stream>>>(W1, W1t, 3072, 1024, 3072);
    transpose_conv_kernel<<<dim3(16, 32), 256, 0, stream>>>(W2, W2t, 1024, 512, 1024);

    pool_kernel<<<dim3(8, BB), 256, 0, stream>>>(enc, pooled);
    embed_kernel<<<dim3(BB * TT), 256, 0, stream>>>(seq, emb, tok);

    // ---- layer 1: xw = tok @ Wi1^T + b (mode-2 perm), then one persistent launch ----
    hipMemsetAsync(hb0, 0, (size_t)2 * BB * UU * 2, stream);
    gemm_tile<<<dim3(16, 128), 256, 0, stream>>>(tok, Wi1t,                    l1f_b, xw,       16384, 2048, 256, 0, 2);
    gemm_tile<<<dim3(16, 128), 256, 0, stream>>>(tok, Wi1t + (size_t)2048*256, l1b_b, xw + XWD, 16384, 2048, 256, 0, 2);
    lstm_seq<<<dim3(32, 4, 2), 512, 0, stream>>>(xw, Wh1t, seq, hb0, hb1, lstm1out, gflags, 0);

    // ---- layer 2 ----
    hipMemsetAsync(hb0, 0, (size_t)2 * BB * UU * 2, stream);
    gemm_tile<<<dim3(16, 128), 256, 0, stream>>>(lstm1out, Wi2t,                     l2f_b, xw,       16384, 2048, 1024, 0, 2);
    gemm_tile<<<dim3(16, 128), 256, 0, stream>>>(lstm1out, Wi2t + (size_t)2048*1024, l2b_b, xw + XWD, 16384, 2048, 1024, 0, 2);
    lstm_seq<<<dim3(32, 4, 2), 512, 0, stream>>>(xw, Wh2t, seq, hb0, hb1, nullptr, gflags, TT);
    // s=63 writes hout=hb0 -> final h2 in hb0

    // ---- head ----
    concat_kernel<<<dim3(BB), 256, 0, stream>>>(pooled, hb0, feats);
    gemm_tile<<<dim3(8, 2), 256, 0, stream>>>(feats, W1t, b1, x1, BB, 1024, 3072, 1, 0);
    gemm_tile<<<dim3(4, 2), 256, 0, stream>>>(x1, W2t, b2, x2, BB, 512, 1024, 1, 0);
    final_kernel<<<dim3(BB), 256, 0, stream>>>(x2, W3, b3, (float*)d_out);
}

// Round 7
// 1505.402 us; speedup vs baseline: 1.7843x; 1.7843x over previous
//
#include <hip/hip_runtime.h>
#include <hip/hip_bf16.h>
#include <math.h>

#define BB 256
#define TT 64
#define UU 512
#define XWD 33554432   // per-dir xw elements (64*256*2048)
#define WSTR 520       // LDS weight row stride (512 + 8 pad)

typedef __hip_bfloat16 bf16;
typedef __attribute__((ext_vector_type(8))) short sh8;     // 8 x bf16
typedef __attribute__((ext_vector_type(4))) short sh4;     // 4 x bf16
typedef __attribute__((ext_vector_type(4))) float floatx4; // MFMA acc
typedef __attribute__((ext_vector_type(4))) unsigned int ui4;

__device__ __forceinline__ float bf2f(short s) {
    union { unsigned int u; float f; } v;
    v.u = ((unsigned int)(unsigned short)s) << 16;
    return v.f;
}
__device__ __forceinline__ short f2bf_bits(float f) {
    union { float f; unsigned u; } v; v.f = f;
    unsigned rr = v.u + 0x7fff + ((v.u >> 16) & 1);   // RNE, matches __float2bfloat16
    return (short)(rr >> 16);
}
__device__ __forceinline__ float fsig(float x)  { return 1.0f / (1.0f + __expf(-x)); }
__device__ __forceinline__ float ftanh(float x) { return 2.0f / (1.0f + __expf(-2.0f * x)) - 1.0f; }

// ---- agent-coherent (MALL-level, fence-free) accesses via sc0 sc1 cache policy ----
union U16 { ui4 u; sh8 s; };

// 8 x 16B coherent loads + single waitcnt, one asm block (no hoist hazard).
__device__ __forceinline__ void coh_load_h8(const bf16* p, sh8 hv[8]) {
    U16 a0, a1, a2, a3, a4, a5, a6, a7;
    asm volatile(
        "global_load_dwordx4 %[o0], %[ad], off sc0 sc1\n\t"
        "global_load_dwordx4 %[o1], %[ad], off offset:64 sc0 sc1\n\t"
        "global_load_dwordx4 %[o2], %[ad], off offset:128 sc0 sc1\n\t"
        "global_load_dwordx4 %[o3], %[ad], off offset:192 sc0 sc1\n\t"
        "global_load_dwordx4 %[o4], %[ad], off offset:256 sc0 sc1\n\t"
        "global_load_dwordx4 %[o5], %[ad], off offset:320 sc0 sc1\n\t"
        "global_load_dwordx4 %[o6], %[ad], off offset:384 sc0 sc1\n\t"
        "global_load_dwordx4 %[o7], %[ad], off offset:448 sc0 sc1\n\t"
        "s_waitcnt vmcnt(0)"
        : [o0]"=&v"(a0.u), [o1]"=&v"(a1.u), [o2]"=&v"(a2.u), [o3]"=&v"(a3.u),
          [o4]"=&v"(a4.u), [o5]"=&v"(a5.u), [o6]"=&v"(a6.u), [o7]"=&v"(a7.u)
        : [ad]"v"(p)
        : "memory");
    hv[0] = a0.s; hv[1] = a1.s; hv[2] = a2.s; hv[3] = a3.s;
    hv[4] = a4.s; hv[5] = a5.s; hv[6] = a6.s; hv[7] = a7.s;
}
__device__ __forceinline__ void coh_store_h(bf16* p, short v) {
    asm volatile("global_store_short %[ad], %[dv], off sc0 sc1"
                 :: [ad]"v"(p), [dv]"v"((unsigned)(unsigned short)v) : "memory");
}
__device__ __forceinline__ void flag_store(unsigned* p, unsigned v) {
    asm volatile("global_store_dword %[ad], %[dv], off sc0 sc1"
                 :: [ad]"v"(p), [dv]"v"(v) : "memory");
}
__device__ __forceinline__ unsigned flag_load(const unsigned* p) {
    unsigned v;
    asm volatile("global_load_dword %[dv], %[ad], off sc0 sc1\n\t"
                 "s_waitcnt vmcnt(0)"
                 : [dv]"=&v"(v) : [ad]"v"(p) : "memory");
    return v;
}

// async global->LDS, 16B per lane. LDS dest must be wave-uniform base + lane*16.
#define GLDS(gp, lp) __builtin_amdgcn_global_load_lds( \
    (const __attribute__((address_space(1))) unsigned int*)(const void*)(gp), \
    (__attribute__((address_space(3))) unsigned int*)(void*)(lp), 16, 0, 0)

// ---------------- transpose + fp32->bf16 convert ----------------
__global__ void transpose_conv_kernel(const float* __restrict__ in, bf16* __restrict__ out,
                                      int K, int N, int out_stride) {
    __shared__ float tile[32][33];
    int k0 = blockIdx.y * 32;
    int n0 = blockIdx.x * 32;
    int tid = threadIdx.x;
    int nn = tid & 31, kk = tid >> 5;
    #pragma unroll
    for (int j = 0; j < 4; ++j)
        tile[kk + j * 8][nn] = in[(size_t)(k0 + kk + j * 8) * N + n0 + nn];
    __syncthreads();
    int kk2 = tid & 31, nn2 = tid >> 5;
    #pragma unroll
    for (int j = 0; j < 4; ++j)
        out[(size_t)(n0 + nn2 + j * 8) * out_stride + k0 + kk2] =
            __float2bfloat16(tile[kk2][nn2 + j * 8]);
}

// ---------------- mean-pool over 10x10 spatial ----------------
__global__ void pool_kernel(const float* __restrict__ enc, float* __restrict__ pooled) {
    int b = blockIdx.y;
    int e = blockIdx.x * 256 + threadIdx.x;
    const float* p = enc + (size_t)b * 100 * 2048 + e;
    float s = 0.f;
    #pragma unroll 4
    for (int i = 0; i < 100; ++i) s += p[(size_t)i * 2048];
    pooled[(size_t)b * 2048 + e] = s * 0.01f;
}

// ---------------- embedding gather -> bf16, [t][b][256] layout ----------------
__global__ void embed_kernel(const int* __restrict__ seq, const float* __restrict__ emb,
                             bf16* __restrict__ tok) {
    int i = blockIdx.x;            // b*T + t
    int e = threadIdx.x;
    int b = i >> 6, t = i & 63;
    tok[((size_t)t * BB + b) * 256 + e] = __float2bfloat16(emb[(size_t)seq[i] * 256 + e]);
}

// ---------------- LDS-staged GEMM: out = act(A @ Wt^T + b) ----------------
__global__ __launch_bounds__(256)
void gemm_tile(const bf16* __restrict__ A, const bf16* __restrict__ Wt,
               const float* __restrict__ bias, bf16* __restrict__ out,
               int M, int N, int K, int relu, int mode) {
    __shared__ __align__(16) bf16 As[128 * 32];
    __shared__ __align__(16) bf16 Bs[128 * 32];
    const int tid = threadIdx.x;
    const int w = tid >> 6, lane = tid & 63;
    const int lm = lane & 15, q = lane >> 4;
    const int m0 = blockIdx.y * 128;
    const int n0 = blockIdx.x * 128;
    const int wm = (w & 1) * 64, wn = (w >> 1) * 64;

    const int srow = tid >> 2;
    const int sk8  = (tid & 3) * 8;
    const bf16* ga0 = A  + (size_t)(m0 + srow) * K + sk8;
    const bf16* ga1 = A  + (size_t)(m0 + 64 + srow) * K + sk8;
    const bf16* gb0 = Wt + (size_t)(n0 + srow) * K + sk8;
    const bf16* gb1 = Wt + (size_t)(n0 + 64 + srow) * K + sk8;
    bf16* la0 = As + tid * 8;
    bf16* la1 = As + 2048 + tid * 8;
    bf16* lb0 = Bs + tid * 8;
    bf16* lb1 = Bs + 2048 + tid * 8;

    floatx4 acc[4][4];
    #pragma unroll
    for (int i = 0; i < 4; ++i)
        #pragma unroll
        for (int j = 0; j < 4; ++j) acc[i][j] = (floatx4){0.f, 0.f, 0.f, 0.f};

    const bf16* ra[4];
    const bf16* rb[4];
    #pragma unroll
    for (int i = 0; i < 4; ++i) ra[i] = As + (wm + i * 16 + lm) * 32 + q * 8;
    #pragma unroll
    for (int j = 0; j < 4; ++j) rb[j] = Bs + (wn + j * 16 + lm) * 32 + q * 8;

    for (int k0 = 0; k0 < K; k0 += 32) {
        GLDS(ga0 + k0, la0);
        GLDS(ga1 + k0, la1);
        GLDS(gb0 + k0, lb0);
        GLDS(gb1 + k0, lb1);
        __syncthreads();
        sh8 af[4], bfr[4];
        #pragma unroll
        for (int i = 0; i < 4; ++i) af[i] = *(const sh8*)ra[i];
        #pragma unroll
        for (int j = 0; j < 4; ++j) bfr[j] = *(const sh8*)rb[j];
        #pragma unroll
        for (int i = 0; i < 4; ++i)
            #pragma unroll
            for (int j = 0; j < 4; ++j)
                acc[i][j] = __builtin_amdgcn_mfma_f32_16x16x32_bf16(af[i], bfr[j], acc[i][j], 0, 0, 0);
        __syncthreads();
    }

    if (mode == 0) {
        #pragma unroll
        for (int i = 0; i < 4; ++i)
            #pragma unroll
            for (int j = 0; j < 4; ++j) {
                int n = n0 + wn + j * 16 + lm;
                float bv = bias[n];
                #pragma unroll
                for (int r = 0; r < 4; ++r) {
                    int m = m0 + wm + i * 16 + q * 4 + r;
                    float v = acc[i][j][r] + bv;
                    if (relu) v = fmaxf(v, 0.f);
                    out[(size_t)m * N + n] = __float2bfloat16(v);
                }
            }
    } else {
        #pragma unroll
        for (int i = 0; i < 4; ++i) {
            int mb = m0 + wm + i * 16 + q * 4;
            int t = mb >> 8;
            int bq = (mb >> 2) & 63;
            #pragma unroll
            for (int j = 0; j < 4; ++j) {
                int n = n0 + wn + j * 16 + lm;
                float bv = bias[n];
                size_t base = ((((size_t)(t * 64 + bq) * 32 + ((n >> 4) & 31)) * 16
                               + (n & 15)) * 16) + (n >> 9) * 4;
                sh4 sv;
                #pragma unroll
                for (int r = 0; r < 4; ++r)
                    sv[r] = f2bf_bits(acc[i][j][r] + bv);
                *(sh4*)(out + base) = sv;
            }
        }
    }
}

// ---------------- fence-free flag barrier (32 x 4B flags in ONE 128B line/group) ------
// All cross-block data (h, flags) uses sc0|sc1 coherent accesses served at the MALL,
// so no wbl2/inv fences are needed. arrive: syncthreads (drains vmcnt -> sc1 h-stores
// complete at MALL) + one sc1 flag store. wait: wave0 lanes poll the line in parallel.
__device__ __forceinline__ void bar_arrive(unsigned* myflag, unsigned val) {
    __syncthreads();
    if (threadIdx.x == 0) flag_store(myflag, val);
}
__device__ __forceinline__ void bar_wait(unsigned* flagbase, unsigned target) {
    if (threadIdx.x < 64) {
        unsigned* my = flagbase + (threadIdx.x & 31);
        for (;;) {
            unsigned v = flag_load(my);
            if (__all(v >= target)) break;
            __builtin_amdgcn_s_sleep(1);
        }
    }
    __syncthreads();
}

// ---------------- persistent LSTM: whole 64-step sequence in one launch ----------------
// grid (32 u-tiles, 4 b-groups, 2 dirs) = 256 blocks, 512 thr, ~100KB LDS -> 1 blk/CU.
// Wh tile + seq tile in LDS; c/h-carry in regs. h exchange via sc1 (MALL-coherent)
// loads/stores + fence-free flag barrier.
__global__ __launch_bounds__(512, 2)
void lstm_seq(const bf16* __restrict__ xw, const bf16* __restrict__ Wht,
              const int* __restrict__ seq, bf16* __restrict__ h0b,
              bf16* __restrict__ h1b, bf16* __restrict__ seqout,
              unsigned* __restrict__ gflags, int tbase) {
    const int dir = blockIdx.z;
    const int u0 = blockIdx.x * 16;
    const int tid = threadIdx.x;
    const int w = tid >> 6, lane = tid & 63;
    const int lm = lane & 15, q = lane >> 4;
    const int kh = w >> 2;           // k-half
    const int wb = w & 3;            // b-group wave
    const int b0blk = blockIdx.y * 64;
    const int b0w = b0blk + wb * 16;
    unsigned* flagbase = gflags + (blockIdx.z * 4 + blockIdx.y) * 32;  // one 128B line
    unsigned* myflag   = flagbase + blockIdx.x;

    __shared__ float part[4 * 64 * 17];          // 17408 B
    __shared__ __align__(16) bf16 lW[64 * WSTR]; // 66560 B
    __shared__ int sq[TT * 64];                  // 16384 B  (~100KB total -> 1 blk/CU)

    const size_t hdb = (size_t)dir * BB * UU;
    const int koff = kh * 256;                   // 8 kc * 32
    const bf16* Wd = Wht + (size_t)dir * 2048 * UU;

    // one-time seq preload: sq[t*64 + bb] = seq[(b0blk+bb)*TT + t]
    for (int i = tid; i < TT * 64; i += 512) {
        int tt = i >> 6, bb = i & 63;
        sq[i] = seq[(b0blk + bb) * TT + tt];
    }
    // one-time weight preload: LDS[g*16+lmr][k] = Wd[(g*512 + u0 + lmr)*512 + k]
    {
        int row = tid >> 3;                  // 0..63
        int ck  = (tid & 7) * 64;
        int g = row >> 4, lmr = row & 15;
        const bf16* gsrc = Wd + (size_t)(g * UU + u0 + lmr) * UU + ck;
        bf16* ldst = lW + row * WSTR + ck;
        #pragma unroll
        for (int j = 0; j < 8; ++j)
            *(sh8*)(ldst + j * 8) = *(const sh8*)(gsrc + j * 8);
    }
    __syncthreads();

    const bf16* lwp0 = lW + (0 * 16 + lm) * WSTR + q * 8 + koff;
    const bf16* lwp1 = lW + (1 * 16 + lm) * WSTR + q * 8 + koff;
    const bf16* lwp2 = lW + (2 * 16 + lm) * WSTR + q * 8 + koff;
    const bf16* lwp3 = lW + (3 * 16 + lm) * WSTR + q * 8 + koff;

    // register state for this lane's (b = b0w + q*4 + r, u = u0 + lm) tile (kh=0 waves)
    float creg[4] = {0.f, 0.f, 0.f, 0.f};
    float hreg[4] = {0.f, 0.f, 0.f, 0.f};

    // xw prefetch for step 0 (kh=0 waves only)
    sh8 x0p = (sh8)0, x1p = (sh8)0;
    if (kh == 0) {
        const int t0s = dir ? (TT - 1) : 0;
        const bf16* xwp = xw + (size_t)dir * XWD
            + (((size_t)(t0s * 64 + (b0w >> 2) + q) * 32 + (u0 >> 4)) * 16 + lm) * 16;
        x0p = *(const sh8*)xwp;
        x1p = *(const sh8*)(xwp + 8);
    }

    for (int s = 0; s < TT; ++s) {
        const int t = dir ? (TT - 1 - s) : s;
        const bf16* hin = (s & 1) ? h1b : h0b;
        bf16*      hout = (s & 1) ? h0b : h1b;

        if (s) bar_wait(flagbase, (unsigned)(tbase + s));

        // coherent h loads: 8x16B issued in one asm block, one waitcnt
        const bf16* hA = hin + hdb + (size_t)(b0w + lm) * UU + q * 8 + koff;
        sh8 hv[8];
        coh_load_h8(hA, hv);

        floatx4 acc0, acc1, acc2, acc3;
        if (kh == 0) {
            acc0 = (floatx4){bf2f(x0p[0]), bf2f(x0p[1]), bf2f(x0p[2]), bf2f(x0p[3])};
            acc1 = (floatx4){bf2f(x0p[4]), bf2f(x0p[5]), bf2f(x0p[6]), bf2f(x0p[7])};
            acc2 = (floatx4){bf2f(x1p[0]), bf2f(x1p[1]), bf2f(x1p[2]), bf2f(x1p[3])};
            acc3 = (floatx4){bf2f(x1p[4]), bf2f(x1p[5]), bf2f(x1p[6]), bf2f(x1p[7])};
        } else {
            acc0 = acc1 = acc2 = acc3 = (floatx4){0.f, 0.f, 0.f, 0.f};
        }

        #pragma unroll
        for (int kc = 0; kc < 8; ++kc) {
            sh8 a0 = *(const sh8*)(lwp0 + kc * 32);
            sh8 a1 = *(const sh8*)(lwp1 + kc * 32);
            sh8 a2 = *(const sh8*)(lwp2 + kc * 32);
            sh8 a3 = *(const sh8*)(lwp3 + kc * 32);
            acc0 = __builtin_amdgcn_mfma_f32_16x16x32_bf16(hv[kc], a0, acc0, 0, 0, 0);
            acc1 = __builtin_amdgcn_mfma_f32_16x16x32_bf16(hv[kc], a1, acc1, 0, 0, 0);
            acc2 = __builtin_amdgcn_mfma_f32_16x16x32_bf16(hv[kc], a2, acc2, 0, 0, 0);
            acc3 = __builtin_amdgcn_mfma_f32_16x16x32_bf16(hv[kc], a3, acc3, 0, 0, 0);
        }

        if (kh == 1) {
            float* pp = part + (wb * 64 + lane) * 17;
            #pragma unroll
            for (int r = 0; r < 4; ++r) {
                pp[r] = acc0[r]; pp[4 + r] = acc1[r];
                pp[8 + r] = acc2[r]; pp[12 + r] = acc3[r];
            }
        }
        __syncthreads();
        if (kh == 0) {
            const float* pp = part + (wb * 64 + lane) * 17;
            #pragma unroll
            for (int r = 0; r < 4; ++r) {
                acc0[r] += pp[r]; acc1[r] += pp[4 + r];
                acc2[r] += pp[8 + r]; acc3[r] += pp[12 + r];
            }
            const int uu = u0 + lm;
            #pragma unroll
            for (int r = 0; r < 4; ++r) {
                int b = b0w + q * 4 + r;
                bool m = (sq[t * 64 + wb * 16 + q * 4 + r] != 0);
                float cp = creg[r];
                float cn = fsig(acc1[r]) * cp + fsig(acc0[r]) * ftanh(acc2[r]);
                float hn = fsig(acc3[r]) * ftanh(cn);
                float hv2 = m ? hn : hreg[r];
                creg[r] = m ? cn : cp;
                hreg[r] = hv2;
                size_t off = hdb + (size_t)b * UU + uu;
                short hb = f2bf_bits(hv2);
                coh_store_h(&hout[off], hb);                       // sc1 -> MALL
                if (seqout)
                    __builtin_nontemporal_store(hb,
                        (short*)&seqout[((size_t)t * BB + b) * 1024 + dir * UU + uu]);
            }
        }
        bar_arrive(myflag, (unsigned)(tbase + s + 1));

        // prefetch next step's xw (h-independent; hides under barrier skew)
        if (kh == 0 && s + 1 < TT) {
            const int tn = dir ? (TT - 2 - s) : (s + 1);
            const bf16* xwp = xw + (size_t)dir * XWD
                + (((size_t)(tn * 64 + (b0w >> 2) + q) * 32 + (u0 >> 4)) * 16 + lm) * 16;
            x0p = *(const sh8*)xwp;
            x1p = *(const sh8*)(xwp + 8);
        }
    }
}

// ---------------- feats = [pooled | h2f | h2b] (bf16) ----------------
__global__ void concat_kernel(const float* __restrict__ pooled, const bf16* __restrict__ h2,
                              bf16* __restrict__ feats) {
    int b = blockIdx.x;
    for (int j = threadIdx.x; j < 3072; j += 256) {
        bf16 v;
        if (j < 2048) v = __float2bfloat16(pooled[(size_t)b * 2048 + j]);
        else {
            int u = j - 2048;
            int dir = u >> 9;
            int uu = u & 511;
            v = h2[((size_t)dir * BB + b) * UU + uu];
        }
        feats[(size_t)b * 3072 + j] = v;
    }
}

// ---------------- out = sigmoid(x2 @ W3 + b3), K=512 ----------------
__global__ void final_kernel(const bf16* __restrict__ x2, const float* __restrict__ W3,
                             const float* __restrict__ b3, float* __restrict__ out) {
    int b = blockIdx.x;
    int tid = threadIdx.x;
    float v = __bfloat162float(x2[(size_t)b * 512 + tid]) * W3[tid]
            + __bfloat162float(x2[(size_t)b * 512 + 256 + tid]) * W3[256 + tid];
    for (int off = 32; off > 0; off >>= 1) v += __shfl_down(v, off, 64);
    __shared__ float wsum[4];
    if ((tid & 63) == 0) wsum[tid >> 6] = v;
    __syncthreads();
    if (tid == 0) {
        float sum = wsum[0] + wsum[1] + wsum[2] + wsum[3] + b3[0];
        out[b] = 1.0f / (1.0f + expf(-sum));
    }
}

extern "C" void kernel_launch(void* const* d_in, const int* in_sizes, int n_in,
                              void* d_out, int out_size, void* d_ws, size_t ws_size,
                              hipStream_t stream) {
    const float* enc    = (const float*)d_in[0];
    const int*   seq    = (const int*)  d_in[1];
    const float* emb    = (const float*)d_in[2];
    const float* l1f_Wi = (const float*)d_in[3];
    const float* l1f_Wh = (const float*)d_in[4];
    const float* l1f_b  = (const float*)d_in[5];
    const float* l1b_Wi = (const float*)d_in[6];
    const float* l1b_Wh = (const float*)d_in[7];
    const float* l1b_b  = (const float*)d_in[8];
    const float* l2f_Wi = (const float*)d_in[9];
    const float* l2f_Wh = (const float*)d_in[10];
    const float* l2f_b  = (const float*)d_in[11];
    const float* l2b_Wi = (const float*)d_in[12];
    const float* l2b_Wh = (const float*)d_in[13];
    const float* l2b_b  = (const float*)d_in[14];
    const float* W1     = (const float*)d_in[15];
    const float* b1     = (const float*)d_in[16];
    const float* W2     = (const float*)d_in[17];
    const float* b2     = (const float*)d_in[18];
    const float* W3     = (const float*)d_in[19];
    const float* b3     = (const float*)d_in[20];

    // ---- workspace layout ----
    char* p = (char*)d_ws;
    bf16* tok      = (bf16*)p;  p += (size_t)TT * BB * 256 * 2;        // [t][b][256]
    bf16* lstm1out = (bf16*)p;  p += (size_t)TT * BB * 1024 * 2;       // [t][b][1024]
    bf16* xw       = (bf16*)p;  p += (size_t)2 * XWD * 2;              // mode-2 perm
    bf16* Wh1t     = (bf16*)p;  p += (size_t)2 * 2048 * 512 * 2;
    bf16* Wh2t     = (bf16*)p;  p += (size_t)2 * 2048 * 512 * 2;
    bf16* Wi1t     = (bf16*)p;  p += (size_t)2 * 2048 * 256 * 2;
    bf16* Wi2t     = (bf16*)p;  p += (size_t)2 * 2048 * 1024 * 2;
    bf16* W1t      = (bf16*)p;  p += (size_t)1024 * 3072 * 2;
    bf16* W2t      = (bf16*)p;  p += (size_t)512 * 1024 * 2;
    float* pooled  = (float*)p; p += (size_t)BB * 2048 * 4;
    bf16* feats    = (bf16*)p;  p += (size_t)BB * 3072 * 2;
    bf16* x1       = (bf16*)p;  p += (size_t)BB * 1024 * 2;
    bf16* x2       = (bf16*)p;  p += (size_t)BB * 512 * 2;
    bf16* hb0      = (bf16*)p;  p += (size_t)2 * BB * UU * 2;
    bf16* hb1      = (bf16*)p;  p += (size_t)2 * BB * UU * 2;
    unsigned* gflags = (unsigned*)p; p += 8 * 128;                     // 8 grp x 1 line

    // ---- one-time setup ----
    hipMemsetAsync(gflags, 0, 8 * 128, stream);

    transpose_conv_kernel<<<dim3(64, 16), 256, 0, stream>>>(l1f_Wh, Wh1t,                    512, 2048, 512);
    transpose_conv_kernel<<<dim3(64, 16), 256, 0, stream>>>(l1b_Wh, Wh1t + (size_t)2048*512, 512, 2048, 512);
    transpose_conv_kernel<<<dim3(64, 16), 256, 0, stream>>>(l2f_Wh, Wh2t,                    512, 2048, 512);
    transpose_conv_kernel<<<dim3(64, 16), 256, 0, stream>>>(l2b_Wh, Wh2t + (size_t)2048*512, 512, 2048, 512);
    transpose_conv_kernel<<<dim3(64, 8),  256, 0, stream>>>(l1f_Wi, Wi1t,                    256, 2048, 256);
    transpose_conv_kernel<<<dim3(64, 8),  256, 0, stream>>>(l1b_Wi, Wi1t + (size_t)2048*256, 256, 2048, 256);
    transpose_conv_kernel<<<dim3(64, 32), 256, 0, stream>>>(l2f_Wi, Wi2t,                     1024, 2048, 1024);
    transpose_conv_kernel<<<dim3(64, 32), 256, 0, stream>>>(l2b_Wi, Wi2t + (size_t)2048*1024, 1024, 2048, 1024);
    transpose_conv_kernel<<<dim3(32, 96), 256, 0, stream>>>(W1, W1t, 3072, 1024, 3072);
    transpose_conv_kernel<<<dim3(16, 32), 256, 0, stream>>>(W2, W2t, 1024, 512, 1024);

    pool_kernel<<<dim3(8, BB), 256, 0, stream>>>(enc, pooled);
    embed_kernel<<<dim3(BB * TT), 256, 0, stream>>>(seq, emb, tok);

    // ---- layer 1: xw = tok @ Wi1^T + b (mode-2 perm), then one persistent launch ----
    hipMemsetAsync(hb0, 0, (size_t)2 * BB * UU * 2, stream);
    gemm_tile<<<dim3(16, 128), 256, 0, stream>>>(tok, Wi1t,                    l1f_b, xw,       16384, 2048, 256, 0, 2);
    gemm_tile<<<dim3(16, 128), 256, 0, stream>>>(tok, Wi1t + (size_t)2048*256, l1b_b, xw + XWD, 16384, 2048, 256, 0, 2);
    lstm_seq<<<dim3(32, 4, 2), 512, 0, stream>>>(xw, Wh1t, seq, hb0, hb1, lstm1out, gflags, 0);

    // ---- layer 2 ----
    hipMemsetAsync(hb0, 0, (size_t)2 * BB * UU * 2, stream);
    gemm_tile<<<dim3(16, 128), 256, 0, stream>>>(lstm1out, Wi2t,                     l2f_b, xw,       16384, 2048, 1024, 0, 2);
    gemm_tile<<<dim3(16, 128), 256, 0, stream>>>(lstm1out, Wi2t + (size_t)2048*1024, l2b_b, xw + XWD, 16384, 2048, 1024, 0, 2);
    lstm_seq<<<dim3(32, 4, 2), 512, 0, stream>>>(xw, Wh2t, seq, hb0, hb1, nullptr, gflags, TT);
    // s=63 writes hout=hb0 -> final h2 in hb0

    // ---- head ----
    concat_kernel<<<dim3(BB), 256, 0, stream>>>(pooled, hb0, feats);
    gemm_tile<<<dim3(8, 2), 256, 0, stream>>>(feats, W1t, b1, x1, BB, 1024, 3072, 1, 0);
    gemm_tile<<<dim3(4, 2), 256, 0, stream>>>(x1, W2t, b2, x2, BB, 512, 1024, 1, 0);
    final_kernel<<<dim3(BB), 256, 0, stream>>>(x2, W3, b3, (float*)d_out);
}